// Round 7
// baseline (25.010 us; speedup 1.0000x reference)
//
#include <hip/hip_runtime.h>

// Problem constants (match the reference file).
#define IN_F   4096
#define OUT_F  4094   // IN_FEATURES - 2
#define BATCH_ 4096
#define WCOLS  3      // min(3, OUT_F)

typedef float f32x4 __attribute__((ext_vector_type(4)));
typedef float f32x2 __attribute__((ext_vector_type(2)));

// ---------------------------------------------------------------------------
// Two rows per 256-thread block (2048 blocks = 8 blocks/CU exactly):
//   - each weight f32x4 load feeds BOTH rows' FMA chains (halves weight vmem)
//   - each thread keeps 2 independent input read streams (8x16B in flight)
//   - zero stores interleaved in the same loop (temporal; nt costs +12 µs,
//     R4 vs R5 A/B — the 128 MiB working set lives in the 256 MiB L3)
//
// Row byte base = b*16376; even rows base%16==0, odd rows base%16==8:
//   row0 (even): scalar col3, f32x4 cols 4..4091 (1022), f32x2 cols 4092..4093
//   row1 (odd):  scalar col3, f32x2 cols 4..5,  f32x4 cols 6..4093 (1022)
// Cols 0..2 of each row written once after the reduction (disjoint addrs).
// ---------------------------------------------------------------------------
__global__ __launch_bounds__(256) void fused_row2_kernel(const float* __restrict__ in,
                                                         const float* __restrict__ w,
                                                         const float* __restrict__ bias,
                                                         float* __restrict__ out) {
    const int fb  = blockIdx.x;          // 0..2047
    const int tid = threadIdx.x;
    const long b0 = 2L * fb;             // even row
    const long b1 = b0 + 1;              // odd row

    const f32x4* __restrict__ row0 = (const f32x4*)(in + b0 * IN_F);
    const f32x4* __restrict__ row1 = (const f32x4*)(in + b1 * IN_F);
    const f32x4* __restrict__ w0   = (const f32x4*)(w);
    const f32x4* __restrict__ w1   = (const f32x4*)(w + IN_F);
    const f32x4* __restrict__ w2   = (const f32x4*)(w + 2 * IN_F);

    float* __restrict__ base0 = out + b0 * OUT_F;   // 16B-aligned
    float* __restrict__ base1 = out + b1 * OUT_F;   // 8 mod 16
    f32x4* __restrict__ zp0 = (f32x4*)(base0 + 4);  // cols 4..4091
    f32x4* __restrict__ zp1 = (f32x4*)(base1 + 6);  // cols 6..4093

    const f32x4 z4 = {0.f, 0.f, 0.f, 0.f};
    const f32x2 z2 = {0.f, 0.f};
    if (tid == 0)   base0[3] = 0.f;
    if (tid == 64)  *(f32x2*)(base0 + 4092) = z2;
    if (tid == 128) base1[3] = 0.f;
    if (tid == 192) *(f32x2*)(base1 + 4) = z2;

    float p0 = 0.f, p1 = 0.f, p2 = 0.f;   // row0 dots
    float q0 = 0.f, q1 = 0.f, q2 = 0.f;   // row1 dots

    // 1024 f32x4 per row; 256 threads -> 4 iterations each, 2 rows/iter.
    #pragma unroll 4
    for (int i = tid; i < IN_F / 4; i += 256) {
        f32x4 x0 = row0[i];
        f32x4 x1 = row1[i];
        f32x4 a  = w0[i];
        f32x4 c  = w1[i];
        f32x4 d  = w2[i];
        if (i < 1022) { zp0[i] = z4; zp1[i] = z4; }
        p0 = fmaf(x0.x, a.x, fmaf(x0.y, a.y, fmaf(x0.z, a.z, fmaf(x0.w, a.w, p0))));
        p1 = fmaf(x0.x, c.x, fmaf(x0.y, c.y, fmaf(x0.z, c.z, fmaf(x0.w, c.w, p1))));
        p2 = fmaf(x0.x, d.x, fmaf(x0.y, d.y, fmaf(x0.z, d.z, fmaf(x0.w, d.w, p2))));
        q0 = fmaf(x1.x, a.x, fmaf(x1.y, a.y, fmaf(x1.z, a.z, fmaf(x1.w, a.w, q0))));
        q1 = fmaf(x1.x, c.x, fmaf(x1.y, c.y, fmaf(x1.z, c.z, fmaf(x1.w, c.w, q1))));
        q2 = fmaf(x1.x, d.x, fmaf(x1.y, d.y, fmaf(x1.z, d.z, fmaf(x1.w, d.w, q2))));
    }

    // Wave-level reduction (wave = 64 lanes on gfx950).
    #pragma unroll
    for (int off = 32; off > 0; off >>= 1) {
        p0 += __shfl_down(p0, off);
        p1 += __shfl_down(p1, off);
        p2 += __shfl_down(p2, off);
        q0 += __shfl_down(q0, off);
        q1 += __shfl_down(q1, off);
        q2 += __shfl_down(q2, off);
    }

    __shared__ float red[4][2 * WCOLS];
    const int wave = tid >> 6;
    const int lane = tid & 63;
    if (lane == 0) {
        red[wave][0] = p0; red[wave][1] = p1; red[wave][2] = p2;
        red[wave][3] = q0; red[wave][4] = q1; red[wave][5] = q2;
    }
    __syncthreads();

    if (tid < WCOLS) {
        float t = red[0][tid] + red[1][tid] + red[2][tid] + red[3][tid];
        base0[tid] = t + (float)IN_F * bias[tid];
    } else if (tid >= 64 && tid < 64 + WCOLS) {
        const int j = tid - 64;
        float t = red[0][3 + j] + red[1][3 + j] + red[2][3 + j] + red[3][3 + j];
        base1[j] = t + (float)IN_F * bias[j];
    }
}

extern "C" void kernel_launch(void* const* d_in, const int* in_sizes, int n_in,
                              void* d_out, int out_size, void* d_ws, size_t ws_size,
                              hipStream_t stream) {
    const float* in   = (const float*)d_in[0];   // (4096, 4096) fp32
    const float* w    = (const float*)d_in[1];   // (4094, 4096) fp32
    const float* bias = (const float*)d_in[2];   // (4094,) fp32
    float* out = (float*)d_out;                  // (4096, 4094) fp32

    fused_row2_kernel<<<BATCH_ / 2, 256, 0, stream>>>(in, w, bias, out);
}

// Round 8
// 24.371 us; speedup vs baseline: 1.0262x; 1.0262x over previous
//
#include <hip/hip_runtime.h>

// Problem constants (match the reference file).
#define IN_F   4096
#define OUT_F  4094   // IN_FEATURES - 2
#define BATCH_ 4096
#define WCOLS  3      // min(3, OUT_F)

typedef float f32x4 __attribute__((ext_vector_type(4)));
typedef float f32x2 __attribute__((ext_vector_type(2)));

// ---------------------------------------------------------------------------
// R6 structure (one 256-thread block per row, fused zero+dot), ONE change:
// stores are NONTEMPORAL, loads stay temporal.
//   A/B vs R6 (24.3 µs): R3/R4 applied nt to BOTH loads and stores (-12 µs);
//   this isolates the store side. Mechanism: nt stores skip L3 allocation so
//   the 64 MiB output stream stops evicting the 64 MiB input from L3
//   (steady-state FETCH=33 MB shows ~50% input miss today).
//
// Row byte base = b*16376; even rows base%16==0, odd rows base%16==8:
//   even: scalar col3, f32x4 cols 4..4091 (1022), f32x2 cols 4092..4093
//   odd:  scalar col3, f32x2 cols 4..5,  f32x4 cols 6..4093 (1022)
// ---------------------------------------------------------------------------
__global__ __launch_bounds__(256) void fused_row_nt_kernel(const float* __restrict__ in,
                                                           const float* __restrict__ w,
                                                           const float* __restrict__ bias,
                                                           float* __restrict__ out) {
    const int b   = blockIdx.x;
    const int tid = threadIdx.x;

    const f32x4* __restrict__ row = (const f32x4*)(in + (long)b * IN_F);
    const f32x4* __restrict__ w0  = (const f32x4*)(w);
    const f32x4* __restrict__ w1  = (const f32x4*)(w + IN_F);
    const f32x4* __restrict__ w2  = (const f32x4*)(w + 2 * IN_F);

    float* __restrict__ base = out + (long)b * OUT_F;
    const int odd = b & 1;
    f32x4* __restrict__ zp = (f32x4*)(base + (odd ? 6 : 4));   // 16B-aligned

    const f32x4 z4 = {0.f, 0.f, 0.f, 0.f};
    const f32x2 z2 = {0.f, 0.f};
    if (tid == 0)  __builtin_nontemporal_store(0.f, &base[3]);
    if (tid == 64) __builtin_nontemporal_store(z2, (f32x2*)(base + (odd ? 4 : 4092)));

    float s0 = 0.f, s1 = 0.f, s2 = 0.f;

    // 1024 f32x4 temporal loads + 1022 f32x4 nt zero-stores, interleaved.
    #pragma unroll 4
    for (int i = tid; i < IN_F / 4; i += 256) {
        f32x4 x = row[i];
        f32x4 a = w0[i];
        f32x4 c = w1[i];
        f32x4 d = w2[i];
        if (i < 1022) __builtin_nontemporal_store(z4, &zp[i]);
        s0 = fmaf(x.x, a.x, fmaf(x.y, a.y, fmaf(x.z, a.z, fmaf(x.w, a.w, s0))));
        s1 = fmaf(x.x, c.x, fmaf(x.y, c.y, fmaf(x.z, c.z, fmaf(x.w, c.w, s1))));
        s2 = fmaf(x.x, d.x, fmaf(x.y, d.y, fmaf(x.z, d.z, fmaf(x.w, d.w, s2))));
    }

    // Wave-level reduction (wave = 64 lanes on gfx950).
    #pragma unroll
    for (int off = 32; off > 0; off >>= 1) {
        s0 += __shfl_down(s0, off);
        s1 += __shfl_down(s1, off);
        s2 += __shfl_down(s2, off);
    }

    __shared__ float red[4][WCOLS];
    const int wave = tid >> 6;
    const int lane = tid & 63;
    if (lane == 0) {
        red[wave][0] = s0;
        red[wave][1] = s1;
        red[wave][2] = s2;
    }
    __syncthreads();

    if (tid < WCOLS) {
        float t = red[0][tid] + red[1][tid] + red[2][tid] + red[3][tid];
        __builtin_nontemporal_store(t + (float)IN_F * bias[tid], &base[tid]);
    }
}

extern "C" void kernel_launch(void* const* d_in, const int* in_sizes, int n_in,
                              void* d_out, int out_size, void* d_ws, size_t ws_size,
                              hipStream_t stream) {
    const float* in   = (const float*)d_in[0];   // (4096, 4096) fp32
    const float* w    = (const float*)d_in[1];   // (4094, 4096) fp32
    const float* bias = (const float*)d_in[2];   // (4094,) fp32
    float* out = (float*)d_out;                  // (4096, 4094) fp32

    fused_row_nt_kernel<<<BATCH_, 256, 0, stream>>>(in, w, bias, out);
}